// Round 4
// baseline (316.922 us; speedup 1.0000x reference)
//
#include <hip/hip_runtime.h>

typedef float v2f __attribute__((ext_vector_type(2)));

#define KS    11
#define HH    512
#define WW    512
#define OUTD  502          // HH - KS + 1
#define GR    11           // rows per staged group
#define NG    5            // groups per band -> ROWS = 55
#define ROWS  55
#define OH    45           // output rows per band (ROWS - 10)
#define NBR   12           // 12*45 = 540 >= 502
#define NBC   2            // column tiles
#define TC    256          // output cols per block
#define SGQ   134          // float2 quads per staged row (covers 268 cols)
#define SGL   268          // staged cols
#define NIMG  96
#define ITEMS (GR * SGQ)   // 1474 staging items per group
#define NIT   6            // ceil(ITEMS/256)

// Streaming separable SSIM, v4.
// r3 lessons: v_pk_fma_f32 is rate-neutral on gfx950 (157 TF = scalar full
// rate) and the asm pinning spilled prefetch regs (WRITE_SIZE 45KB->20MB);
// 32B-stride b128 staging writes caused 2.1M bank-conflict cycles.
// This version:
//  - 4 convolutions, not 5: SSIM only uses sigma_x^2+sigma_y^2 as a SUM,
//    so conv(x^2)+conv(y^2) == conv(x^2+y^2). Quantities: x, y, s=x2+y2, p=xy.
//  - h-register ring (44 floats): vertical conv runs only for the 45 output
//    rows, not all 55 staged rows (was 44 V-fmas on every staged row).
//  - plain scalar fp32, no asm; double-buffered 11-row LDS groups -> one
//    barrier per group; 16B/lane staging writes (conflict-free).
__global__ __launch_bounds__(256, 3)
void ssim_main(const float* __restrict__ xg, const float* __restrict__ yg,
               const float* __restrict__ win, double* __restrict__ acc_out)
{
    __shared__ v2f buf[2][GR][SGL];   // (x,y) pairs, double-buffered group
    __shared__ float wsums[4];

    const int tid = threadIdx.x;
    int bb = blockIdx.x;
    const int img  = bb % NIMG;  bb /= NIMG;
    const int band = bb % NBR;   bb /= NBR;
    const int cb   = bb * TC;
    const int row0 = band * OH;

    // 1D gaussian = row sums of the rank-1, normalized 2D window.
    // win + uniform index -> scalar loads, g[] lives in SGPRs.
    float g[KS];
    #pragma unroll
    for (int i = 0; i < KS; i++) {
        float s = 0.f;
        #pragma unroll
        for (int j = 0; j < KS; j++) s += win[i * KS + j];
        g[i] = s;
    }

    const float* xi = xg + (size_t)img * (HH * WW);
    const float* yi = yg + (size_t)img * (HH * WW);

    // staging: item = (row i, quad k) -> 2 staged cols; float2 global loads,
    // one b128 LDS write per item (16B/lane stride across lanes: no conflicts)
    float2 pfx[NIT], pfy[NIT];
    auto prefetch = [&](int gidx) {
        #pragma unroll
        for (int it = 0; it < NIT; it++) {
            const int idx = tid + 256 * it;
            if (idx < ITEMS) {
                int i = idx / SGQ, k = idx - i * SGQ;
                int gr = row0 + gidx * GR + i; if (gr > HH - 1) gr = HH - 1;
                int gc = cb + 2 * k;           if (gc > WW - 2) gc = WW - 2;
                const size_t base = (size_t)gr * WW + gc;
                pfx[it] = *(const float2*)(xi + base);
                pfy[it] = *(const float2*)(yi + base);
            }
        }
    };
    auto store_s = [&](int bsel) {
        #pragma unroll
        for (int it = 0; it < NIT; it++) {
            const int idx = tid + 256 * it;
            if (idx < ITEMS) {
                int i = idx / SGQ, k = idx - i * SGQ;
                float4 w; w.x = pfx[it].x; w.y = pfy[it].x;
                          w.z = pfx[it].y; w.w = pfy[it].y;
                *(float4*)&buf[bsel][i][2 * k] = w;   // ds_write_b128
            }
        }
    };

    // h-value register ring: 4 quantities x 11 rows, slot = global row % 11
    float rh[4][KS];
    #pragma unroll
    for (int q = 0; q < 4; q++)
        #pragma unroll
        for (int s = 0; s < KS; s++) rh[q][s] = 0.f;

    float ssum = 0.f;
    const float C1 = 0.0001f;   // (0.01)^2
    const float C2 = 0.0009f;   // (0.03)^2
    const bool colvalid = (cb + tid) < OUTD;

    // horizontal 11-tap conv of (x, y, s=x2+y2, p=xy) at this thread's column
    auto hpass = [&](const v2f* rowp, int rr) {
        float hx = 0.f, hy = 0.f, hs = 0.f, hp = 0.f;
        #pragma unroll
        for (int j = 0; j < KS; j++) {
            const v2f v = rowp[j];                    // ds_read_b64, stride-1
            const float s = fmaf(v.y, v.y, v.x * v.x);
            const float p = v.x * v.y;
            hx = fmaf(g[j], v.x, hx);
            hy = fmaf(g[j], v.y, hy);
            hs = fmaf(g[j], s,   hs);
            hp = fmaf(g[j], p,   hp);
        }
        rh[0][rr] = hx; rh[1][rr] = hy; rh[2][rr] = hs; rh[3][rr] = hp;
    };
    // vertical 11-tap conv from the ring + SSIM epilogue (rr compile-time)
    auto vpass = [&](int rr, int jout) {
        float mx = 0.f, my = 0.f, S = 0.f, P = 0.f;
        #pragma unroll
        for (int i = 0; i < KS; i++) {
            const int sl = (rr + 1 + i) % KS;
            mx = fmaf(g[i], rh[0][sl], mx);
            my = fmaf(g[i], rh[1][sl], my);
            S  = fmaf(g[i], rh[2][sl], S);
            P  = fmaf(g[i], rh[3][sl], P);
        }
        if (jout < OUTD && colvalid) {
            const float mxx = mx * mx, myy = my * my, mxy = mx * my;
            const float ssig = S - mxx - myy;         // sigma_x^2 + sigma_y^2
            const float sxy  = P - mxy;
            const float num = (2.f * mxy + C1) * (2.f * sxy + C2);
            const float den = (mxx + myy + C1) * (ssig + C2);
            float rc = __builtin_amdgcn_rcpf(den);
            rc = rc * fmaf(-den, rc, 2.0f);           // one NR step
            ssum = fmaf(num, rc, ssum);
        }
    };

    prefetch(0); store_s(0); prefetch(1);
    __syncthreads();

    // ---- group 0 (peeled: rows 0..9 have no completed output) ----
    {
        store_s(1);
        prefetch(2);
        const v2f (*bufc)[SGL] = buf[0];
        #pragma unroll
        for (int rr = 0; rr < GR; rr++) {
            hpass(&bufc[rr][tid], rr);
            if (rr == GR - 1) vpass(rr, row0);   // first output row
        }
        __syncthreads();
    }
    // ---- groups 1..NG-1: every row completes an output ----
    #pragma unroll 1
    for (int gi = 1; gi < NG; gi++) {
        if (gi + 1 < NG) store_s((gi + 1) & 1);
        if (gi + 2 < NG) prefetch(gi + 2);
        const v2f (*bufc)[SGL] = buf[gi & 1];
        const int jbase = row0 + gi * GR - (KS - 1);
        #pragma unroll
        for (int rr = 0; rr < GR; rr++) {
            hpass(&bufc[rr][tid], rr);
            vpass(rr, jbase + rr);
        }
        __syncthreads();
    }

    // block reduction: wave shuffle, then cross-wave via LDS
    #pragma unroll
    for (int off = 32; off > 0; off >>= 1)
        ssum += __shfl_down(ssum, off);
    const int wave = tid >> 6;
    if ((tid & 63) == 0) wsums[wave] = ssum;
    __syncthreads();
    if (tid == 0) {
        float s = wsums[0] + wsums[1] + wsums[2] + wsums[3];
        atomicAdd(acc_out, (double)s);
    }
}

__global__ void ssim_finalize(const double* __restrict__ acc, float* __restrict__ out)
{
    // total outputs: 96 * 502 * 502 = 24,192,384
    out[0] = (float)(acc[0] * (1.0 / 24192384.0));
}

extern "C" void kernel_launch(void* const* d_in, const int* in_sizes, int n_in,
                              void* d_out, int out_size, void* d_ws, size_t ws_size,
                              hipStream_t stream)
{
    const float* x   = (const float*)d_in[0];
    const float* y   = (const float*)d_in[1];
    const float* win = (const float*)d_in[2];
    float* out = (float*)d_out;
    double* acc = (double*)d_ws;

    hipMemsetAsync(acc, 0, sizeof(double), stream);
    ssim_main<<<dim3(NIMG * NBR * NBC), dim3(256), 0, stream>>>(x, y, win, acc);
    ssim_finalize<<<dim3(1), dim3(1), 0, stream>>>(acc, out);
}

// Round 5
// 290.126 us; speedup vs baseline: 1.0924x; 1.0924x over previous
//
#include <hip/hip_runtime.h>

#define KS    11
#define HH    512
#define WW    512
#define OUTD  502          // HH - KS + 1
#define GR    11           // rows per staged group
#define NG    5            // groups per band -> ROWS = 55
#define OH    45           // output rows per band (55 - 10)
#define NBR   12           // 12*45 = 540 >= 502
#define NBC   2            // column tiles
#define TC    256          // output cols per block
#define ROWF  272          // floats per staged row (68 chunks x 4, >= 266)
#define CHK   68           // 16B chunks per row
#define QTOT  (GR * CHK)   // 748 chunks per group per array
#define GFL   3072         // floats per group buffer (768 chunks, padded)
#define NIMG  96

#define AS1 __attribute__((address_space(1)))
#define AS3 __attribute__((address_space(3)))

// Streaming separable SSIM, v5.
// r3/r4 lesson: register-prefetch of staging data across barriers ALWAYS
// spills here (WRITE_SIZE 20MB/41MB scratch traffic). Fix: async DMA
// global->LDS (__builtin_amdgcn_global_load_lds, 16B/lane) -> zero staging
// registers, no ds_write, no spill. DMA lands lane-contiguous, so x and y
// live in separate LDS buffers; tap reads are b32/read2 pairs.
// Kept from v4: 4 convolutions (conv(x^2)+conv(y^2) == conv(x^2+y^2)),
// h-register ring with vertical pass only on output rows, 11-row
// double-buffered groups, one barrier per group.
__global__ __launch_bounds__(256, 3)
void ssim_main(const float* __restrict__ xg, const float* __restrict__ yg,
               const float* __restrict__ win, double* __restrict__ acc_out)
{
    __shared__ float xbuf[2][GFL];
    __shared__ float ybuf[2][GFL];
    __shared__ float wsums[4];

    const int tid = threadIdx.x;
    int bb = blockIdx.x;
    const int img  = bb % NIMG;  bb /= NIMG;
    const int band = bb % NBR;   bb /= NBR;
    const int cb   = bb * TC;
    const int row0 = band * OH;

    // 1D gaussian = row sums of the rank-1, normalized 2D window.
    // Uniform indices -> scalar loads; g[] lives in SGPRs.
    float g[KS];
    #pragma unroll
    for (int i = 0; i < KS; i++) {
        float s = 0.f;
        #pragma unroll
        for (int j = 0; j < KS; j++) s += win[i * KS + j];
        g[i] = s;
    }

    const float* xi = xg + (size_t)img * (HH * WW);
    const float* yi = yg + (size_t)img * (HH * WW);

    // Async DMA one 11-row group (x and y) into buffer bsel.
    // chunk q -> row i=q/68, chunk k=q%68; LDS float idx 4q = i*272+4k.
    // All 3 iterations run full-wave (q up to 767 lands in the pad, with
    // clamped-but-valid global addresses) -> no divergent DMA.
    auto dma_group = [&](int gidx, int bsel) {
        #pragma unroll
        for (int it = 0; it < 3; it++) {
            const int q = tid + 256 * it;
            int i = q / CHK, k = q - i * CHK;
            int gr = row0 + gidx * GR + i; if (gr > HH - 1) gr = HH - 1;
            int gc = cb + 4 * k;           if (gc > WW - 4) gc = WW - 4;
            const size_t gofs = (size_t)gr * WW + gc;
            __builtin_amdgcn_global_load_lds(
                (AS1 const void*)(xi + gofs), (AS3 void*)&xbuf[bsel][4 * q], 16, 0, 0);
            __builtin_amdgcn_global_load_lds(
                (AS1 const void*)(yi + gofs), (AS3 void*)&ybuf[bsel][4 * q], 16, 0, 0);
        }
    };

    // h-value register ring: 4 quantities x 11 rows, slot = local row % 11
    float rh[4][KS];
    #pragma unroll
    for (int q = 0; q < 4; q++)
        #pragma unroll
        for (int s = 0; s < KS; s++) rh[q][s] = 0.f;

    float ssum = 0.f;
    const float C1 = 0.0001f;   // (0.01)^2
    const float C2 = 0.0009f;   // (0.03)^2
    const bool colvalid = (cb + tid) < OUTD;

    // horizontal 11-tap conv of (x, y, s=x2+y2, p=xy) at this thread's column
    auto hpass = [&](const float* Xr, const float* Yr, int rr) {
        float hx = 0.f, hy = 0.f, hs = 0.f, hp = 0.f;
        #pragma unroll
        for (int j = 0; j < KS; j++) {
            const float xj = Xr[j], yj = Yr[j];
            hx = fmaf(g[j], xj, hx);
            hy = fmaf(g[j], yj, hy);
            hs = fmaf(g[j], fmaf(xj, xj, yj * yj), hs);
            hp = fmaf(g[j], xj * yj, hp);
        }
        rh[0][rr] = hx; rh[1][rr] = hy; rh[2][rr] = hs; rh[3][rr] = hp;
    };
    // vertical 11-tap conv from the ring + SSIM epilogue (rr compile-time)
    auto vpass = [&](int rr, int jout) {
        if (jout < OUTD) {                      // block-uniform guard
            float mx = 0.f, my = 0.f, S = 0.f, P = 0.f;
            #pragma unroll
            for (int i = 0; i < KS; i++) {
                const int sl = (rr + 1 + i) % KS;
                mx = fmaf(g[i], rh[0][sl], mx);
                my = fmaf(g[i], rh[1][sl], my);
                S  = fmaf(g[i], rh[2][sl], S);
                P  = fmaf(g[i], rh[3][sl], P);
            }
            if (colvalid) {
                const float mxx = mx * mx, myy = my * my, mxy = mx * my;
                const float ssig = S - mxx - myy;     // sigma_x^2 + sigma_y^2
                const float sxy  = P - mxy;
                const float num = (2.f * mxy + C1) * (2.f * sxy + C2);
                const float den = (mxx + myy + C1) * (ssig + C2);
                float rc = __builtin_amdgcn_rcpf(den);
                rc = rc * fmaf(-den, rc, 2.0f);       // one NR step
                ssum = fmaf(num, rc, ssum);
            }
        }
    };

    dma_group(0, 0);
    __syncthreads();                  // vmcnt(0) drain: buf0 ready

    // ---- group 0 (peeled: only rr==10 completes an output row) ----
    {
        dma_group(1, 1);
        const float* X = &xbuf[0][0];
        const float* Y = &ybuf[0][0];
        #pragma unroll
        for (int rr = 0; rr < GR; rr++) {
            hpass(X + rr * ROWF + tid, Y + rr * ROWF + tid, rr);
            if (rr == GR - 1) vpass(rr, row0);
        }
        __syncthreads();              // buf1 DMA done; all waves done w/ buf0
    }
    // ---- groups 1..NG-1: every row completes an output ----
    #pragma unroll 1
    for (int gi = 1; gi < NG; gi++) {
        if (gi + 1 < NG) dma_group(gi + 1, (gi + 1) & 1);
        const float* X = &xbuf[gi & 1][0];
        const float* Y = &ybuf[gi & 1][0];
        const int jbase = row0 + gi * GR - (KS - 1);
        #pragma unroll
        for (int rr = 0; rr < GR; rr++) {
            hpass(X + rr * ROWF + tid, Y + rr * ROWF + tid, rr);
            vpass(rr, jbase + rr);
        }
        __syncthreads();
    }

    // block reduction: wave shuffle, then cross-wave via LDS
    #pragma unroll
    for (int off = 32; off > 0; off >>= 1)
        ssum += __shfl_down(ssum, off);
    const int wave = tid >> 6;
    if ((tid & 63) == 0) wsums[wave] = ssum;
    __syncthreads();
    if (tid == 0) {
        float s = wsums[0] + wsums[1] + wsums[2] + wsums[3];
        atomicAdd(acc_out, (double)s);
    }
}

__global__ void ssim_finalize(const double* __restrict__ acc, float* __restrict__ out)
{
    // total outputs: 96 * 502 * 502 = 24,192,384
    out[0] = (float)(acc[0] * (1.0 / 24192384.0));
}

extern "C" void kernel_launch(void* const* d_in, const int* in_sizes, int n_in,
                              void* d_out, int out_size, void* d_ws, size_t ws_size,
                              hipStream_t stream)
{
    const float* x   = (const float*)d_in[0];
    const float* y   = (const float*)d_in[1];
    const float* win = (const float*)d_in[2];
    float* out = (float*)d_out;
    double* acc = (double*)d_ws;

    hipMemsetAsync(acc, 0, sizeof(double), stream);
    ssim_main<<<dim3(NIMG * NBR * NBC), dim3(256), 0, stream>>>(x, y, win, acc);
    ssim_finalize<<<dim3(1), dim3(1), 0, stream>>>(acc, out);
}